// Round 4
// baseline (390.266 us; speedup 1.0000x reference)
//
#include <hip/hip_runtime.h>
#include <math.h>

#define EPSF 1e-10f

typedef int   vi4 __attribute__((ext_vector_type(4)));
typedef float vf4 __attribute__((ext_vector_type(4)));

struct Pair { float term; int parent; };  // merged 8 B record: one load per walk step

static __device__ __forceinline__ unsigned short f32_to_bf16(float f) {
    unsigned int u = __float_as_uint(f);
    u += 0x7fffu + ((u >> 16) & 1u);   // RNE; inputs finite
    return (unsigned short)(u >> 16);
}
static __device__ __forceinline__ float bf16_to_f32(unsigned short h) {
    return __uint_as_float(((unsigned int)h) << 16);
}

// Kernel 1: feature transform + linear + sigmoid -> pairs[i] = {diff[i]*score, parent[i]}
__global__ __launch_bounds__(256) void term_kernel(
    const float* __restrict__ diff,
    const float* __restrict__ attr,    // N x 15 row-major
    const float* __restrict__ weight,  // 17
    const float* __restrict__ bias,    // 1
    const int*   __restrict__ parent,
    Pair* __restrict__ pairs, int N)
{
    int i = blockIdx.x * blockDim.x + threadIdx.x;
    if (i >= N) return;
    const float* a = attr + (long long)i * 15;
    float f[15];
#pragma unroll
    for (int k = 0; k < 15; ++k) f[k] = a[k];

    float acc = bias[0];
#pragma unroll
    for (int k = 0; k < 5; ++k) acc += f[k] * weight[k];          // raw 0..4
#pragma unroll
    for (int k = 0; k < 9; ++k)                                   // log(|attr 6..14|+eps)
        acc += __logf(fabsf(f[6 + k]) + EPSF) * weight[5 + k];
    acc += (sqrtf(f[7]) / (sqrtf(f[6]) + EPSF)) * weight[14];     // lshape
    acc += __cosf(f[5]) * weight[15];
    acc += __sinf(f[5]) * weight[16];

    float sig = 1.0f / (1.0f + __expf(-acc));
    Pair pr; pr.term = diff[i] * sig; pr.parent = parent[i];
    pairs[i] = pr;
}

// Phase 0: simple per-node walk to root (lo==0 region is small and L2-hot).
__global__ __launch_bounds__(256) void chain_phase0(
    const Pair* __restrict__ pairs,
    float* __restrict__ nv,
    unsigned short* __restrict__ nvb,
    int hi)
{
    int i = blockIdx.x * blockDim.x + threadIdx.x;
    if (i >= hi) return;
    float s = 0.0f;
    int j = i;
    while (j >= 0) {
        Pair pr = pairs[j];
        s += pr.term;
        j = pr.parent;
    }
    nv[i] = s;
    nvb[i] = f32_to_bf16(s);
}

// Later phases: per-lane state machine processing G nodes SEQUENTIALLY.
// Wave iterates ~max-over-lanes of (sum of G walk lengths) instead of
// G * max-over-lanes — divergence averages out across a lane's G nodes.
// Each phase's pairs window is <= 4 MB so it stays resident in per-XCD L2.
template <int G>
__global__ __launch_bounds__(256) void chain_phase_multi(
    const Pair* __restrict__ pairs,
    float* __restrict__ nv,            // f32 prefix sums (cross-phase lookup)
    unsigned short* __restrict__ nvb,  // bf16 copy for the gather kernel
    int lo, int hi)
{
    int T = gridDim.x * blockDim.x;
    int t = blockIdx.x * blockDim.x + threadIdx.x;
    int g = 0;
    int i = lo + t;
    float s = 0.0f;
    int j = (i < hi) ? i : -2;         // -2 => no node, skip store on finalize
    while (__any(g < G)) {
        if (g < G) {
            if (j >= lo) {             // walk step (one 8 B random load)
                Pair pr = pairs[j];
                s += pr.term;
                j = pr.parent;
            } else {                   // finalize current node, start next
                if (j != -2) {
                    float r = s + ((j >= 0) ? nv[j] : 0.0f);
                    nv[i] = r;
                    nvb[i] = f32_to_bf16(r);
                }
                ++g;
                if (g < G) {
                    i = lo + t + g * T;
                    s = 0.0f;
                    j = (i < hi) ? i : -2;
                }
            }
        }
    }
}

// Kernel 3: out[p] = bf16->f32(nvb[pixel_node[p]]). 16 independent gathers per
// iteration to maximize MLP (latency-bound random access into L2-resident 4 MB).
__global__ __launch_bounds__(256) void gather_kernel(
    const unsigned short* __restrict__ nvb,
    const int* __restrict__ pixel_node,
    float* __restrict__ out, long long M)
{
    long long idx = (long long)blockIdx.x * blockDim.x + threadIdx.x;
    long long stride = (long long)gridDim.x * blockDim.x;
    long long M16 = M >> 4;
    const vi4* pn4 = (const vi4*)pixel_node;
    vf4* out4 = (vf4*)out;
    for (long long t = idx; t < M16; t += stride) {
        vi4 p0 = __builtin_nontemporal_load(pn4 + 4 * t + 0);
        vi4 p1 = __builtin_nontemporal_load(pn4 + 4 * t + 1);
        vi4 p2 = __builtin_nontemporal_load(pn4 + 4 * t + 2);
        vi4 p3 = __builtin_nontemporal_load(pn4 + 4 * t + 3);
        vf4 v0, v1, v2, v3;
        v0.x = bf16_to_f32(nvb[p0.x]); v0.y = bf16_to_f32(nvb[p0.y]);
        v0.z = bf16_to_f32(nvb[p0.z]); v0.w = bf16_to_f32(nvb[p0.w]);
        v1.x = bf16_to_f32(nvb[p1.x]); v1.y = bf16_to_f32(nvb[p1.y]);
        v1.z = bf16_to_f32(nvb[p1.z]); v1.w = bf16_to_f32(nvb[p1.w]);
        v2.x = bf16_to_f32(nvb[p2.x]); v2.y = bf16_to_f32(nvb[p2.y]);
        v2.z = bf16_to_f32(nvb[p2.z]); v2.w = bf16_to_f32(nvb[p2.w]);
        v3.x = bf16_to_f32(nvb[p3.x]); v3.y = bf16_to_f32(nvb[p3.y]);
        v3.z = bf16_to_f32(nvb[p3.w == p3.w ? p3.z : p3.z]); v3.w = bf16_to_f32(nvb[p3.w]);
        __builtin_nontemporal_store(v0, out4 + 4 * t + 0);
        __builtin_nontemporal_store(v1, out4 + 4 * t + 1);
        __builtin_nontemporal_store(v2, out4 + 4 * t + 2);
        __builtin_nontemporal_store(v3, out4 + 4 * t + 3);
    }
    for (long long t = (M16 << 4) + idx; t < M; t += stride)
        out[t] = bf16_to_f32(nvb[pixel_node[t]]);
}

extern "C" void kernel_launch(void* const* d_in, const int* in_sizes, int n_in,
                              void* d_out, int out_size, void* d_ws, size_t ws_size,
                              hipStream_t stream) {
    const float* diff   = (const float*)d_in[0];
    const float* attr   = (const float*)d_in[1];
    const float* weight = (const float*)d_in[2];
    const float* bias   = (const float*)d_in[3];
    const int*   parent = (const int*)d_in[4];
    const int*   pixel  = (const int*)d_in[5];
    float* out = (float*)d_out;

    int N = in_sizes[0];
    Pair*           pairs = (Pair*)d_ws;                      // N * 8 B
    float*          nv    = (float*)(pairs + N);              // N * 4 B
    unsigned short* nvb   = (unsigned short*)(nv + N);        // N * 2 B

    int blocks = (N + 255) / 256;
    term_kernel<<<blocks, 256, 0, stream>>>(diff, attr, weight, bias, parent, pairs, N);

    // Phase boundaries: windows of <= 4 MB of pairs each (per-XCD L2-resident).
    int B0 = N < (1 << 18) ? N : (1 << 18);          // 256K  (2 MB window, full walk)
    int B1 = N < (1 << 19) ? N : (1 << 19);          // 512K  (2 MB)
    int B2 = N < (1 << 20) ? N : (1 << 20);          // 1M    (4 MB)
    int B3 = N < 3 * (1 << 19) ? N : 3 * (1 << 19);  // 1.5M  (4 MB)
    int B4 = N;                                      //       (4 MB)

    chain_phase0<<<(B0 + 255) / 256, 256, 0, stream>>>(pairs, nv, nvb, B0);
    if (B1 > B0) {
        int th = (B1 - B0 + 1) / 2;
        chain_phase_multi<2><<<(th + 255) / 256, 256, 0, stream>>>(pairs, nv, nvb, B0, B1);
    }
    if (B2 > B1) {
        int th = (B2 - B1 + 1) / 2;
        chain_phase_multi<2><<<(th + 255) / 256, 256, 0, stream>>>(pairs, nv, nvb, B1, B2);
    }
    if (B3 > B2) {
        int th = (B3 - B2 + 1) / 2;
        chain_phase_multi<2><<<(th + 255) / 256, 256, 0, stream>>>(pairs, nv, nvb, B2, B3);
    }
    if (B4 > B3) {
        int th = (B4 - B3 + 1) / 2;
        chain_phase_multi<2><<<(th + 255) / 256, 256, 0, stream>>>(pairs, nv, nvb, B3, B4);
    }

    gather_kernel<<<4096, 256, 0, stream>>>(nvb, pixel, out, (long long)out_size);
}